// Round 4
// baseline (471.511 us; speedup 1.0000x reference)
//
#include <hip/hip_runtime.h>

#define N_NODES 100000
#define N_EDGES 1600000
#define D 128
#define RPB 64            // node rows per bucket
#define NBUCKET 1563      // ceil(N_NODES / RPB)
#define BCAP 1400         // bucket capacity (Poisson mean 1024, +11 sigma)

constexpr float LN_EPS   = 1e-5f;
constexpr float MEAN_EPS = 1e-8f;

typedef __attribute__((ext_vector_type(8))) short bf16x8;
typedef __attribute__((ext_vector_type(4))) float f32x4;

__device__ inline float bf2f(unsigned short h) {
  union { unsigned u; float f; } v; v.u = (unsigned)h << 16; return v.f;
}
__device__ inline unsigned short f2bf(float f) {
  union { float f; unsigned u; } v; v.f = f;
  return (unsigned short)((v.u + 0x7FFFu + ((v.u >> 16) & 1u)) >> 16);
}

// ---------------------------------------------------------------------------
// x (fp32) -> x_bf16
// ---------------------------------------------------------------------------
__global__ __launch_bounds__(256) void xconv_kernel(const float* __restrict__ x,
                                                    unsigned short* __restrict__ xb) {
  int i = blockIdx.x * 256 + threadIdx.x;
  if (i >= N_NODES * D / 4) return;
  float4 v = ((const float4*)x)[i];
  ushort4 o;
  o.x = f2bf(v.x); o.y = f2bf(v.y); o.z = f2bf(v.z); o.w = f2bf(v.w);
  ((ushort4*)xb)[i] = o;
}

// [W_self | W_agg] -> bf16 concat [128][256]; bsum = bself + bagg
__global__ __launch_bounds__(256) void wconv_kernel(
    const float* __restrict__ Wself, const float* __restrict__ Wagg,
    const float* __restrict__ bself, const float* __restrict__ bagg,
    unsigned short* __restrict__ wcat, float* __restrict__ bsum) {
  int t = blockIdx.x * 256 + threadIdx.x;
  if (t < 128 * 256) {
    int o = t >> 8, k = t & 255;
    float v = (k < 128) ? Wself[o * 128 + k] : Wagg[o * 128 + (k - 128)];
    wcat[o * 256 + k] = f2bf(v);
  }
  if (t < 128) bsum[t] = bself[t] + bagg[t];
}

// ---------------------------------------------------------------------------
// Partition edges into fixed-capacity buckets of RPB destination rows.
// Entry = (lrow<<17)|col packed in 4B; writes within a bucket are dense ->
// ~16 entries per 64B line instead of 1 write per line (the R3 killer).
// ---------------------------------------------------------------------------
__global__ __launch_bounds__(256) void bucket_scatter(const int* __restrict__ ei,
                                                      int* __restrict__ bcnt,
                                                      unsigned* __restrict__ buckets) {
  int e = blockIdx.x * 256 + threadIdx.x;
  if (e >= N_EDGES) return;
  int row = ei[e];
  int col = ei[N_EDGES + e];
  int b = row >> 6;
  int pos = atomicAdd(&bcnt[b], 1);
  if (pos < BCAP)
    buckets[(size_t)b * BCAP + pos] = ((unsigned)(row & 63) << 17) | (unsigned)col;
}

// ---------------------------------------------------------------------------
// Fused local-CSR build (in LDS) + pull-mode mean aggregation.
// One block per bucket. Counting sort in LDS (hist -> scan -> scatter), then
// each wave aggregates 16 rows: 4 lane-groups x 16 lanes x uint4 keep 4
// gathered x-rows in flight per instruction. Mean written bf16 into the
// first 256B of the node's d_out row (overwritten later by the gemm).
// ---------------------------------------------------------------------------
__global__ __launch_bounds__(256) void aggregate_bucket(
    const unsigned short* __restrict__ xb, const int* __restrict__ bcnt,
    const unsigned* __restrict__ buckets, float* out) {
  __shared__ int cnt_s[RPB];
  __shared__ int off_s[RPB];
  __shared__ int cur_s[RPB];
  __shared__ int col_s[BCAP];

  const int b = blockIdx.x;
  const int t = threadIdx.x;
  int n = bcnt[b]; if (n > BCAP) n = BCAP;
  const unsigned* bk = buckets + (size_t)b * BCAP;

  if (t < RPB) cnt_s[t] = 0;
  __syncthreads();
  for (int i = t; i < n; i += 256)
    atomicAdd(&cnt_s[bk[i] >> 17], 1);
  __syncthreads();

  // exclusive scan over RPB entries
  if (t < RPB) off_s[t] = cnt_s[t];
  __syncthreads();
  for (int off = 1; off < RPB; off <<= 1) {
    int u = 0;
    if (t < RPB && t >= off) u = off_s[t - off];
    __syncthreads();
    if (t < RPB) off_s[t] += u;
    __syncthreads();
  }
  int excl = 0;
  if (t < RPB) excl = off_s[t] - cnt_s[t];
  __syncthreads();
  if (t < RPB) { off_s[t] = excl; cur_s[t] = excl; }
  __syncthreads();

  // LDS scatter: col list grouped by local row
  for (int i = t; i < n; i += 256) {
    unsigned e = bk[i];
    int pos = atomicAdd(&cur_s[e >> 17], 1);
    col_s[pos] = (int)(e & 0x1FFFFu);
  }
  __syncthreads();

  // aggregation
  const int w = t >> 6, lane = t & 63;
  const int grp = lane >> 4, l = lane & 15;
  const int nodebase = b << 6;
  for (int lrow = w; lrow < RPB; lrow += 4) {
    int node = nodebase + lrow;
    if (node >= N_NODES) break;
    int beg = off_s[lrow];
    int deg = cnt_s[lrow];
    float acc[8];
#pragma unroll
    for (int k = 0; k < 8; ++k) acc[k] = 0.f;
    for (int j0 = 0; j0 < deg; j0 += 4) {
      int jj = j0 + grp;
      if (jj < deg) {
        int col = col_s[beg + jj];
        uint4 p = *(const uint4*)(xb + (size_t)col * D + l * 8);
        acc[0] += bf2f((unsigned short)(p.x & 0xFFFFu));
        acc[1] += bf2f((unsigned short)(p.x >> 16));
        acc[2] += bf2f((unsigned short)(p.y & 0xFFFFu));
        acc[3] += bf2f((unsigned short)(p.y >> 16));
        acc[4] += bf2f((unsigned short)(p.z & 0xFFFFu));
        acc[5] += bf2f((unsigned short)(p.z >> 16));
        acc[6] += bf2f((unsigned short)(p.w & 0xFFFFu));
        acc[7] += bf2f((unsigned short)(p.w >> 16));
      }
    }
#pragma unroll
    for (int k = 0; k < 8; ++k) {
      acc[k] += __shfl_xor(acc[k], 16, 64);
      acc[k] += __shfl_xor(acc[k], 32, 64);
    }
    if (grp == 0) {
      float inv = 1.0f / ((float)deg + MEAN_EPS);
      uint4 o;
      o.x = (unsigned)f2bf(acc[0] * inv) | ((unsigned)f2bf(acc[1] * inv) << 16);
      o.y = (unsigned)f2bf(acc[2] * inv) | ((unsigned)f2bf(acc[3] * inv) << 16);
      o.z = (unsigned)f2bf(acc[4] * inv) | ((unsigned)f2bf(acc[5] * inv) << 16);
      o.w = (unsigned)f2bf(acc[6] * inv) | ((unsigned)f2bf(acc[7] * inv) << 16);
      ((uint4*)(out + (size_t)node * D))[l] = o;
    }
  }
}

// ---------------------------------------------------------------------------
// MFMA GEMM: C[100000x128] = [x_bf16 | mean_bf16] (K=256) @ Wcat^T
// (unchanged from R3)
// ---------------------------------------------------------------------------
__global__ __launch_bounds__(512) void gemm_mfma_ln(
    const unsigned short* __restrict__ xb, const float* out_mean,
    const unsigned short* __restrict__ wcat, const float* __restrict__ bsum,
    const float* __restrict__ gamma, const float* __restrict__ beta,
    float* out) {
  __shared__ unsigned short As[128 * 264];
  __shared__ unsigned short Bs[128 * 264];
  __shared__ float bias_s[128];

  const int t = threadIdx.x;
  const int w = t >> 6, lane = t & 63;
  const int q = lane >> 4, s = lane & 15;
  const int base = blockIdx.x * 128;

  if (t < 128) bias_s[t] = bsum[t];

#pragma unroll
  for (int r = 0; r < 8; ++r) {
    int f = r * 512 + t;
    int row = f >> 5, c = f & 31;
    uint4 v = *(const uint4*)(wcat + row * 256 + c * 8);
    *(uint4*)(Bs + row * 264 + c * 8) = v;
  }
#pragma unroll
  for (int r = 0; r < 8; ++r) {
    int f = r * 512 + t;
    int row = f >> 5, c = f & 31;
    int node = base + row;
    uint4 v = make_uint4(0, 0, 0, 0);
    if (node < N_NODES) {
      const unsigned short* src = (c < 16)
          ? xb + (size_t)node * 128 + c * 8
          : (const unsigned short*)(out_mean + (size_t)node * 128) + (c - 16) * 8;
      v = *(const uint4*)src;
    }
    *(uint4*)(As + row * 264 + c * 8) = v;
  }
  __syncthreads();

  const int mrow = (w & 3) * 32;
  const int ncol = (w >> 2) * 64;

  f32x4 acc[2][4];
#pragma unroll
  for (int i = 0; i < 2; ++i)
#pragma unroll
    for (int j = 0; j < 4; ++j) acc[i][j] = (f32x4)(0.0f);

#pragma unroll
  for (int kk = 0; kk < 8; ++kk) {
    int ko = kk * 32 + q * 8;
    bf16x8 a0 = *(const bf16x8*)(As + (mrow + s) * 264 + ko);
    bf16x8 a1 = *(const bf16x8*)(As + (mrow + 16 + s) * 264 + ko);
    bf16x8 bv[4];
#pragma unroll
    for (int j = 0; j < 4; ++j)
      bv[j] = *(const bf16x8*)(Bs + (ncol + j * 16 + s) * 264 + ko);
#pragma unroll
    for (int j = 0; j < 4; ++j) {
      acc[0][j] = __builtin_amdgcn_mfma_f32_16x16x32_bf16(a0, bv[j], acc[0][j], 0, 0, 0);
      acc[1][j] = __builtin_amdgcn_mfma_f32_16x16x32_bf16(a1, bv[j], acc[1][j], 0, 0, 0);
    }
  }
  __syncthreads();

  float* hS = (float*)As;  // [128][132]
#pragma unroll
  for (int i = 0; i < 2; ++i)
#pragma unroll
    for (int j = 0; j < 4; ++j)
#pragma unroll
      for (int r = 0; r < 4; ++r) {
        int row = mrow + i * 16 + q * 4 + r;
        int col = ncol + j * 16 + s;
        float h = acc[i][j][r] + bias_s[col];
        hS[row * 132 + col] = fmaxf(h, 0.0f);
      }
  __syncthreads();

  float gx = gamma[2 * lane], gy = gamma[2 * lane + 1];
  float bx = beta[2 * lane],  by = beta[2 * lane + 1];
#pragma unroll 4
  for (int rr = 0; rr < 16; ++rr) {
    int row = w * 16 + rr;
    int node = base + row;
    float v0 = hS[row * 132 + 2 * lane];
    float v1 = hS[row * 132 + 2 * lane + 1];
    float s1 = v0 + v1, s2 = v0 * v0 + v1 * v1;
#pragma unroll
    for (int m = 1; m < 64; m <<= 1) {
      s1 += __shfl_xor(s1, m, 64);
      s2 += __shfl_xor(s2, m, 64);
    }
    float mu = s1 * (1.0f / 128.0f);
    float var = s2 * (1.0f / 128.0f) - mu * mu;
    float rstd = rsqrtf(var + LN_EPS);
    if (node < N_NODES) {
      float2 o;
      o.x = (v0 - mu) * rstd * gx + bx;
      o.y = (v1 - mu) * rstd * gy + by;
      *(float2*)(out + (size_t)node * 128 + 2 * lane) = o;
    }
  }
}

extern "C" void kernel_launch(void* const* d_in, const int* in_sizes, int n_in,
                              void* d_out, int out_size, void* d_ws, size_t ws_size,
                              hipStream_t stream) {
  const float* x     = (const float*)d_in[0];
  const int*   ei    = (const int*)d_in[1];
  const float* Wagg  = (const float*)d_in[2];
  const float* bagg  = (const float*)d_in[3];
  const float* Wself = (const float*)d_in[4];
  const float* bself = (const float*)d_in[5];
  const float* gamma = (const float*)d_in[6];
  const float* beta  = (const float*)d_in[7];
  float* out = (float*)d_out;

  // ws layout: x_bf16 | wcat | bsum | bcnt | buckets   (~34.4 MB; R1 proved ws >= 51 MB)
  unsigned short* xb   = (unsigned short*)d_ws;            // 25.6 MB
  unsigned short* wcat = xb + (size_t)N_NODES * D;         // 64 KB
  float* bsum      = (float*)(wcat + 128 * 256);           // 512 B
  int* bcnt        = (int*)(bsum + 128);                   // NBUCKET ints
  unsigned* buckets = (unsigned*)(bcnt + ((NBUCKET + 127) & ~127)); // 8.75 MB

  hipMemsetAsync(bcnt, 0, NBUCKET * sizeof(int), stream);

  xconv_kernel<<<(N_NODES * D / 4 + 255) / 256, 256, 0, stream>>>(x, xb);
  wconv_kernel<<<128, 256, 0, stream>>>(Wself, Wagg, bself, bagg, wcat, bsum);

  bucket_scatter<<<(N_EDGES + 255) / 256, 256, 0, stream>>>(ei, bcnt, buckets);
  aggregate_bucket<<<NBUCKET, 256, 0, stream>>>(xb, bcnt, buckets, out);

  gemm_mfma_ln<<<(N_NODES + 127) / 128, 512, 0, stream>>>(
      xb, out, wcat, bsum, gamma, beta, out);
}

// Round 5
// 281.919 us; speedup vs baseline: 1.6725x; 1.6725x over previous
//
#include <hip/hip_runtime.h>

#define N_NODES 100000
#define N_EDGES 1600000
#define D 128
#define RPB 64                       // node rows per bucket
#define NBUCKET 1563                 // ceil(N_NODES / RPB)
#define NBLK 196                     // partition blocks
#define EPB 8192                     // edges per partition block (196*8192 >= N_EDGES)
#define M_HIST (NBUCKET * NBLK)      // 306348 (block-cursor matrix, [bucket][block])
#define NPART ((M_HIST + 255) / 256) // 1197
#define AGG_CAP 2048                 // max edges per bucket (mean 1024, +32 sigma)

constexpr float LN_EPS   = 1e-5f;
constexpr float MEAN_EPS = 1e-8f;

typedef __attribute__((ext_vector_type(8))) short bf16x8;
typedef __attribute__((ext_vector_type(4))) float f32x4;

__device__ inline float bf2f(unsigned short h) {
  union { unsigned u; float f; } v; v.u = (unsigned)h << 16; return v.f;
}
__device__ inline unsigned short f2bf(float f) {
  union { float f; unsigned u; } v; v.f = f;
  return (unsigned short)((v.u + 0x7FFFu + ((v.u >> 16) & 1u)) >> 16);
}

// ---------------------------------------------------------------------------
// x (fp32) -> x_bf16
// ---------------------------------------------------------------------------
__global__ __launch_bounds__(256) void xconv_kernel(const float* __restrict__ x,
                                                    unsigned short* __restrict__ xb) {
  int i = blockIdx.x * 256 + threadIdx.x;
  if (i >= N_NODES * D / 4) return;
  float4 v = ((const float4*)x)[i];
  ushort4 o;
  o.x = f2bf(v.x); o.y = f2bf(v.y); o.z = f2bf(v.z); o.w = f2bf(v.w);
  ((ushort4*)xb)[i] = o;
}

// [W_self | W_agg] -> bf16 concat [128][256]; bsum = bself + bagg
__global__ __launch_bounds__(256) void wconv_kernel(
    const float* __restrict__ Wself, const float* __restrict__ Wagg,
    const float* __restrict__ bself, const float* __restrict__ bagg,
    unsigned short* __restrict__ wcat, float* __restrict__ bsum) {
  int t = blockIdx.x * 256 + threadIdx.x;
  if (t < 128 * 256) {
    int o = t >> 8, k = t & 255;
    float v = (k < 128) ? Wself[o * 128 + k] : Wagg[o * 128 + (k - 128)];
    wcat[o * 256 + k] = f2bf(v);
  }
  if (t < 128) bsum[t] = bself[t] + bagg[t];
}

// ---------------------------------------------------------------------------
// Deterministic partition, pass A: per-block histogram over buckets.
// hist[bucket][block]; every cell written (zeros included) -> no memset.
// ---------------------------------------------------------------------------
__global__ __launch_bounds__(256) void partA_hist(const int* __restrict__ ei,
                                                  int* __restrict__ hist) {
  __shared__ int cnt_s[NBUCKET];
  const int t = threadIdx.x;
  for (int b = t; b < NBUCKET; b += 256) cnt_s[b] = 0;
  __syncthreads();
  const int base4 = blockIdx.x * (EPB / 4);
  const int lim4 = N_EDGES / 4;
#pragma unroll
  for (int k = 0; k < EPB / 1024; ++k) {
    int i4 = base4 + k * 256 + t;
    if (i4 < lim4) {
      int4 r = ((const int4*)ei)[i4];
      atomicAdd(&cnt_s[r.x >> 6], 1);
      atomicAdd(&cnt_s[r.y >> 6], 1);
      atomicAdd(&cnt_s[r.z >> 6], 1);
      atomicAdd(&cnt_s[r.w >> 6], 1);
    }
  }
  __syncthreads();
  for (int b = t; b < NBUCKET; b += 256)
    hist[b * NBLK + blockIdx.x] = cnt_s[b];
}

// ---------------------------------------------------------------------------
// Exclusive scan over M_HIST ints (3-kernel structure, proven in R2/R3)
// ---------------------------------------------------------------------------
__global__ __launch_bounds__(256) void scan_partials(const int* __restrict__ in,
                                                     int* __restrict__ partials) {
  __shared__ int s[256];
  int i = blockIdx.x * 256 + threadIdx.x;
  s[threadIdx.x] = (i < M_HIST) ? in[i] : 0;
  __syncthreads();
  for (int off = 128; off > 0; off >>= 1) {
    if (threadIdx.x < off) s[threadIdx.x] += s[threadIdx.x + off];
    __syncthreads();
  }
  if (threadIdx.x == 0) partials[blockIdx.x] = s[0];
}

__global__ __launch_bounds__(256) void scan_block(int* __restrict__ partials) {
  __shared__ int s[256];
  __shared__ int carry;
  if (threadIdx.x == 0) carry = 0;
  __syncthreads();
  for (int base = 0; base < NPART; base += 256) {
    int i = base + threadIdx.x;
    int v = (i < NPART) ? partials[i] : 0;
    s[threadIdx.x] = v;
    __syncthreads();
    for (int off = 1; off < 256; off <<= 1) {
      int t = (threadIdx.x >= off) ? s[threadIdx.x - off] : 0;
      __syncthreads();
      s[threadIdx.x] += t;
      __syncthreads();
    }
    int excl = s[threadIdx.x] - v + carry;
    if (i < NPART) partials[i] = excl;
    __syncthreads();
    if (threadIdx.x == 0) carry += s[255];
    __syncthreads();
  }
}

__global__ __launch_bounds__(256) void scan_final(const int* __restrict__ in,
                                                  const int* __restrict__ partials,
                                                  int* __restrict__ scanned) {
  __shared__ int s[256];
  int i = blockIdx.x * 256 + threadIdx.x;
  int v = (i < M_HIST) ? in[i] : 0;
  s[threadIdx.x] = v;
  __syncthreads();
  for (int off = 1; off < 256; off <<= 1) {
    int t = (threadIdx.x >= off) ? s[threadIdx.x - off] : 0;
    __syncthreads();
    s[threadIdx.x] += t;
    __syncthreads();
  }
  if (i < M_HIST) scanned[i] = s[threadIdx.x] - v + partials[blockIdx.x];
}

// ---------------------------------------------------------------------------
// Pass B: place edges into dense per-(block,bucket) reserved ranges.
// LDS cursors only (no global atomics, no cross-XCD line bouncing).
// Entry = (row&63)<<17 | col  (col < 2^17).
// ---------------------------------------------------------------------------
__global__ __launch_bounds__(256) void partB_scatter(const int* __restrict__ ei,
                                                     const int* __restrict__ scanned,
                                                     unsigned* __restrict__ edges_part) {
  __shared__ int cur_s[NBUCKET];
  const int t = threadIdx.x;
  for (int b = t; b < NBUCKET; b += 256)
    cur_s[b] = scanned[b * NBLK + blockIdx.x];
  __syncthreads();
  const int base4 = blockIdx.x * (EPB / 4);
  const int lim4 = N_EDGES / 4;
#pragma unroll
  for (int k = 0; k < EPB / 1024; ++k) {
    int i4 = base4 + k * 256 + t;
    if (i4 < lim4) {
      int4 r = ((const int4*)ei)[i4];
      int4 c = ((const int4*)(ei + N_EDGES))[i4];
      int p0 = atomicAdd(&cur_s[r.x >> 6], 1);
      edges_part[p0] = ((unsigned)(r.x & 63) << 17) | (unsigned)c.x;
      int p1 = atomicAdd(&cur_s[r.y >> 6], 1);
      edges_part[p1] = ((unsigned)(r.y & 63) << 17) | (unsigned)c.y;
      int p2 = atomicAdd(&cur_s[r.z >> 6], 1);
      edges_part[p2] = ((unsigned)(r.z & 63) << 17) | (unsigned)c.z;
      int p3 = atomicAdd(&cur_s[r.w >> 6], 1);
      edges_part[p3] = ((unsigned)(r.w & 63) << 17) | (unsigned)c.w;
    }
  }
}

// ---------------------------------------------------------------------------
// Local counting sort (LDS) + pull-mode mean aggregation. One block/bucket.
// Mean written bf16 into the first 256B of the node's d_out row.
// ---------------------------------------------------------------------------
__global__ __launch_bounds__(256) void aggregate_bucket(
    const unsigned short* __restrict__ xb, const int* __restrict__ scanned,
    const unsigned* __restrict__ edges_part, float* out) {
  __shared__ int cnt_s[RPB];
  __shared__ int off_s[RPB];
  __shared__ int cur_s[RPB];
  __shared__ unsigned ent_s[AGG_CAP];
  __shared__ int col_s[AGG_CAP];

  const int b = blockIdx.x;
  const int t = threadIdx.x;
  const int beg = scanned[b * NBLK];
  const int end = (b == NBUCKET - 1) ? N_EDGES : scanned[(b + 1) * NBLK];
  int n = end - beg; if (n > AGG_CAP) n = AGG_CAP;

  if (t < RPB) cnt_s[t] = 0;
  __syncthreads();
  for (int i = t; i < n; i += 256) {
    unsigned e = edges_part[beg + i];
    ent_s[i] = e;
    atomicAdd(&cnt_s[e >> 17], 1);
  }
  __syncthreads();

  // exclusive scan over RPB entries
  if (t < RPB) off_s[t] = cnt_s[t];
  __syncthreads();
  for (int off = 1; off < RPB; off <<= 1) {
    int u = 0;
    if (t < RPB && t >= off) u = off_s[t - off];
    __syncthreads();
    if (t < RPB) off_s[t] += u;
    __syncthreads();
  }
  int excl = 0;
  if (t < RPB) excl = off_s[t] - cnt_s[t];
  __syncthreads();
  if (t < RPB) { off_s[t] = excl; cur_s[t] = excl; }
  __syncthreads();

  for (int i = t; i < n; i += 256) {
    unsigned e = ent_s[i];
    int pos = atomicAdd(&cur_s[e >> 17], 1);
    col_s[pos] = (int)(e & 0x1FFFFu);
  }
  __syncthreads();

  // aggregation: wave w -> rows w, w+4, ...; 4 lane-groups x 16 lanes x uint4
  const int w = t >> 6, lane = t & 63;
  const int grp = lane >> 4, l = lane & 15;
  const int nodebase = b << 6;
  for (int lrow = w; lrow < RPB; lrow += 4) {
    int node = nodebase + lrow;
    if (node >= N_NODES) break;
    int rbeg = off_s[lrow];
    int deg = cnt_s[lrow];
    float acc[8];
#pragma unroll
    for (int k = 0; k < 8; ++k) acc[k] = 0.f;
    for (int j0 = 0; j0 < deg; j0 += 4) {
      int jj = j0 + grp;
      if (jj < deg) {
        int col = col_s[rbeg + jj];
        uint4 p = *(const uint4*)(xb + (size_t)col * D + l * 8);
        acc[0] += bf2f((unsigned short)(p.x & 0xFFFFu));
        acc[1] += bf2f((unsigned short)(p.x >> 16));
        acc[2] += bf2f((unsigned short)(p.y & 0xFFFFu));
        acc[3] += bf2f((unsigned short)(p.y >> 16));
        acc[4] += bf2f((unsigned short)(p.z & 0xFFFFu));
        acc[5] += bf2f((unsigned short)(p.z >> 16));
        acc[6] += bf2f((unsigned short)(p.w & 0xFFFFu));
        acc[7] += bf2f((unsigned short)(p.w >> 16));
      }
    }
#pragma unroll
    for (int k = 0; k < 8; ++k) {
      acc[k] += __shfl_xor(acc[k], 16, 64);
      acc[k] += __shfl_xor(acc[k], 32, 64);
    }
    if (grp == 0) {
      float inv = 1.0f / ((float)deg + MEAN_EPS);
      uint4 o;
      o.x = (unsigned)f2bf(acc[0] * inv) | ((unsigned)f2bf(acc[1] * inv) << 16);
      o.y = (unsigned)f2bf(acc[2] * inv) | ((unsigned)f2bf(acc[3] * inv) << 16);
      o.z = (unsigned)f2bf(acc[4] * inv) | ((unsigned)f2bf(acc[5] * inv) << 16);
      o.w = (unsigned)f2bf(acc[6] * inv) | ((unsigned)f2bf(acc[7] * inv) << 16);
      ((uint4*)(out + (size_t)node * D))[l] = o;
    }
  }
}

// ---------------------------------------------------------------------------
// MFMA GEMM: C[100000x128] = [x_bf16 | mean_bf16] (K=256) @ Wcat^T  + LN
// (unchanged from R3/R4)
// ---------------------------------------------------------------------------
__global__ __launch_bounds__(512) void gemm_mfma_ln(
    const unsigned short* __restrict__ xb, const float* out_mean,
    const unsigned short* __restrict__ wcat, const float* __restrict__ bsum,
    const float* __restrict__ gamma, const float* __restrict__ beta,
    float* out) {
  __shared__ unsigned short As[128 * 264];
  __shared__ unsigned short Bs[128 * 264];
  __shared__ float bias_s[128];

  const int t = threadIdx.x;
  const int w = t >> 6, lane = t & 63;
  const int q = lane >> 4, s = lane & 15;
  const int base = blockIdx.x * 128;

  if (t < 128) bias_s[t] = bsum[t];

#pragma unroll
  for (int r = 0; r < 8; ++r) {
    int f = r * 512 + t;
    int row = f >> 5, c = f & 31;
    uint4 v = *(const uint4*)(wcat + row * 256 + c * 8);
    *(uint4*)(Bs + row * 264 + c * 8) = v;
  }
#pragma unroll
  for (int r = 0; r < 8; ++r) {
    int f = r * 512 + t;
    int row = f >> 5, c = f & 31;
    int node = base + row;
    uint4 v = make_uint4(0, 0, 0, 0);
    if (node < N_NODES) {
      const unsigned short* src = (c < 16)
          ? xb + (size_t)node * 128 + c * 8
          : (const unsigned short*)(out_mean + (size_t)node * 128) + (c - 16) * 8;
      v = *(const uint4*)src;
    }
    *(uint4*)(As + row * 264 + c * 8) = v;
  }
  __syncthreads();

  const int mrow = (w & 3) * 32;
  const int ncol = (w >> 2) * 64;

  f32x4 acc[2][4];
#pragma unroll
  for (int i = 0; i < 2; ++i)
#pragma unroll
    for (int j = 0; j < 4; ++j) acc[i][j] = (f32x4)(0.0f);

#pragma unroll
  for (int kk = 0; kk < 8; ++kk) {
    int ko = kk * 32 + q * 8;
    bf16x8 a0 = *(const bf16x8*)(As + (mrow + s) * 264 + ko);
    bf16x8 a1 = *(const bf16x8*)(As + (mrow + 16 + s) * 264 + ko);
    bf16x8 bv[4];
#pragma unroll
    for (int j = 0; j < 4; ++j)
      bv[j] = *(const bf16x8*)(Bs + (ncol + j * 16 + s) * 264 + ko);
#pragma unroll
    for (int j = 0; j < 4; ++j) {
      acc[0][j] = __builtin_amdgcn_mfma_f32_16x16x32_bf16(a0, bv[j], acc[0][j], 0, 0, 0);
      acc[1][j] = __builtin_amdgcn_mfma_f32_16x16x32_bf16(a1, bv[j], acc[1][j], 0, 0, 0);
    }
  }
  __syncthreads();

  float* hS = (float*)As;  // [128][132]
#pragma unroll
  for (int i = 0; i < 2; ++i)
#pragma unroll
    for (int j = 0; j < 4; ++j)
#pragma unroll
      for (int r = 0; r < 4; ++r) {
        int row = mrow + i * 16 + q * 4 + r;
        int col = ncol + j * 16 + s;
        float h = acc[i][j][r] + bias_s[col];
        hS[row * 132 + col] = fmaxf(h, 0.0f);
      }
  __syncthreads();

  float gx = gamma[2 * lane], gy = gamma[2 * lane + 1];
  float bx = beta[2 * lane],  by = beta[2 * lane + 1];
#pragma unroll 4
  for (int rr = 0; rr < 16; ++rr) {
    int row = w * 16 + rr;
    int node = base + row;
    float v0 = hS[row * 132 + 2 * lane];
    float v1 = hS[row * 132 + 2 * lane + 1];
    float s1 = v0 + v1, s2 = v0 * v0 + v1 * v1;
#pragma unroll
    for (int m = 1; m < 64; m <<= 1) {
      s1 += __shfl_xor(s1, m, 64);
      s2 += __shfl_xor(s2, m, 64);
    }
    float mu = s1 * (1.0f / 128.0f);
    float var = s2 * (1.0f / 128.0f) - mu * mu;
    float rstd = rsqrtf(var + LN_EPS);
    if (node < N_NODES) {
      float2 o;
      o.x = (v0 - mu) * rstd * gx + bx;
      o.y = (v1 - mu) * rstd * gy + by;
      *(float2*)(out + (size_t)node * 128 + 2 * lane) = o;
    }
  }
}

extern "C" void kernel_launch(void* const* d_in, const int* in_sizes, int n_in,
                              void* d_out, int out_size, void* d_ws, size_t ws_size,
                              hipStream_t stream) {
  const float* x     = (const float*)d_in[0];
  const int*   ei    = (const int*)d_in[1];
  const float* Wagg  = (const float*)d_in[2];
  const float* bagg  = (const float*)d_in[3];
  const float* Wself = (const float*)d_in[4];
  const float* bself = (const float*)d_in[5];
  const float* gamma = (const float*)d_in[6];
  const float* beta  = (const float*)d_in[7];
  float* out = (float*)d_out;

  // ws: xb | wcat | bsum | hist | partials | scanned | edges_part  (~36 MB)
  unsigned short* xb   = (unsigned short*)d_ws;            // 25.6 MB
  unsigned short* wcat = xb + (size_t)N_NODES * D;         // 64 KB
  float* bsum      = (float*)(wcat + 128 * 256);           // 512 B
  int* hist        = (int*)(bsum + 128);                   // M_HIST ints
  int* partials    = hist + M_HIST;                        // NPART (pad 1280)
  int* scanned     = partials + 1280;                      // M_HIST ints
  unsigned* edges_part = (unsigned*)(scanned + M_HIST);    // N_EDGES (6.4 MB)

  xconv_kernel<<<(N_NODES * D / 4 + 255) / 256, 256, 0, stream>>>(x, xb);
  wconv_kernel<<<128, 256, 0, stream>>>(Wself, Wagg, bself, bagg, wcat, bsum);

  partA_hist<<<NBLK, 256, 0, stream>>>(ei, hist);
  scan_partials<<<NPART, 256, 0, stream>>>(hist, partials);
  scan_block<<<1, 256, 0, stream>>>(partials);
  scan_final<<<NPART, 256, 0, stream>>>(hist, partials, scanned);
  partB_scatter<<<NBLK, 256, 0, stream>>>(ei, scanned, edges_part);

  aggregate_bucket<<<NBUCKET, 256, 0, stream>>>(xb, scanned, edges_part, out);

  gemm_mfma_ln<<<(N_NODES + 127) / 128, 512, 0, stream>>>(
      xb, out, wcat, bsum, gamma, beta, out);
}